// Round 12
// baseline (247.109 us; speedup 1.0000x reference)
//
#include <hip/hip_runtime.h>
#include <cmath>

#define S_LEN 2048
#define EMB   1024
#define NHEAD 16
#define DHEAD 64

typedef __attribute__((ext_vector_type(8)))  short bf16x8;
typedef __attribute__((ext_vector_type(4)))  short bf16x4;
typedef __attribute__((ext_vector_type(4)))  float f32x4;
typedef __attribute__((ext_vector_type(16))) float f32x16;

#define MFMA32(a,b,c) __builtin_amdgcn_mfma_f32_32x32x16_bf16(a,b,c,0,0,0)

__device__ __forceinline__ unsigned short f2bf(float f){
    union { float f; unsigned u; } v; v.f = f;
    unsigned r = v.u + 0x7fffu + ((v.u >> 16) & 1u);
    return (unsigned short)(r >> 16);
}

__device__ __forceinline__ unsigned pk2bf(float a, float b){
#if __has_builtin(__builtin_amdgcn_cvt_pk_bf16_f32)
    typedef __attribute__((ext_vector_type(2))) __bf16 bf2;
    bf2 r = __builtin_amdgcn_cvt_pk_bf16_f32(a, b);
    return *(unsigned*)&r;
#else
    return (unsigned)f2bf(a) | ((unsigned)f2bf(b) << 16);
#endif
}

__device__ __forceinline__ float fast_exp2(float x){
#if __has_builtin(__builtin_amdgcn_exp2f)
    return __builtin_amdgcn_exp2f(x);
#else
    return exp2f(x);
#endif
}

__device__ __forceinline__ float fast_rcp(float x){
#if __has_builtin(__builtin_amdgcn_rcpf)
    return __builtin_amdgcn_rcpf(x);
#else
    return 1.0f / x;
#endif
}

// ---------------- fused prep: range-dispatched over blockIdx.x (unchanged, passing) -------
__global__ void prep_all(const float* __restrict__ q, const float* __restrict__ k,
                         const float* __restrict__ v, const int* __restrict__ mask,
                         const float* __restrict__ W,
                         unsigned short* __restrict__ Qb, unsigned short* __restrict__ Kb,
                         unsigned short* __restrict__ Vt, unsigned short* __restrict__ Wb,
                         unsigned* __restrict__ Mb){
    __shared__ unsigned short tile[64*68];
    const int b = blockIdx.x, tid = threadIdx.x;
    if (b < 4096){
        const float SC = 0.045084220027780106f;   // log2(e)/32
        int base = (b*256 + tid) * 4;
        int e = base & (EMB - 1);
        int s = (base >> 10) & (S_LEN - 1);
        int n = base >> 21;
        int h = e >> 6, d = e & 63;
        int dst = ((n*NHEAD + h)*S_LEN + s)*DHEAD + d;
        float4 qv = *(const float4*)(q + base);
        float4 kv = *(const float4*)(k + base);
        uint2 qp, kp;
        qp.x = pk2bf(qv.x*SC, qv.y*SC);
        qp.y = pk2bf(qv.z*SC, qv.w*SC);
        kp.x = pk2bf(kv.x, kv.y);
        kp.y = pk2bf(kv.z, kv.w);
        *(uint2*)(Qb + dst) = qp;
        *(uint2*)(Kb + dst) = kp;
    } else if (b < 5120){
        int idx = b - 4096;
        int st = idx & 31, h = (idx >> 5) & 15, n = idx >> 9;
        int sbase = st * 64;
#pragma unroll
        for (int i = 0; i < 4; i++){
            int c = tid + i*256;
            int srow = c >> 4, c4 = (c & 15) * 4;
            float4 x = *(const float4*)(v + (n*S_LEN + sbase + srow)*EMB + h*DHEAD + c4);
            uint2 p;
            p.x = pk2bf(x.x, x.y);
            p.y = pk2bf(x.z, x.w);
            *(uint2*)&tile[srow*68 + c4] = p;
        }
        __syncthreads();
#pragma unroll
        for (int i = 0; i < 2; i++){
            int c = tid + i*256;
            int d = c >> 3, s8 = (c & 7) * 8;
            unsigned u0 = (unsigned)tile[(s8+0)*68 + d] | ((unsigned)tile[(s8+1)*68 + d] << 16);
            unsigned u1 = (unsigned)tile[(s8+2)*68 + d] | ((unsigned)tile[(s8+3)*68 + d] << 16);
            unsigned u2 = (unsigned)tile[(s8+4)*68 + d] | ((unsigned)tile[(s8+5)*68 + d] << 16);
            unsigned u3 = (unsigned)tile[(s8+6)*68 + d] | ((unsigned)tile[(s8+7)*68 + d] << 16);
            uint4 pk; pk.x = u0; pk.y = u1; pk.z = u2; pk.w = u3;
            *(uint4*)(Vt + ((n*NHEAD + h)*DHEAD + d)*S_LEN + sbase + s8) = pk;
        }
    } else if (b < 6144){
        int base = ((b - 5120)*256 + tid) * 4;
        float4 x = *(const float4*)(W + base);
        uint2 p;
        p.x = pk2bf(x.x, x.y);
        p.y = pk2bf(x.z, x.w);
        *(uint2*)(Wb + base) = p;
    } else {
        int u = (b - 6144)*256 + tid;                 // [0, 262144)
        const int4* m4 = (const int4*)mask + (size_t)u*8;
        unsigned w = 0;
#pragma unroll
        for (int i = 0; i < 8; i++){
            int4 m = m4[i];
            unsigned nib = (m.x ? 1u : 0u) | (m.y ? 2u : 0u) | (m.z ? 4u : 0u) | (m.w ? 8u : 0u);
            w |= nib << (i*4);
        }
        Mb[u] = w;
    }
}

// ---------------- flash attention: 4-wave blocks, 128 q-rows, 2 blocks/CU -----------------
// Round-11 counters (MfmaUtil 28%, VALU 45%, Occupancy 19%, MFMA-busy 17 us + VALU-busy
// 27 us vs dur 61 us) = latency-bound at 1 block/CU (2 waves/SIMD): the 4-deep dependent
// MFMA chains + serial softmax have nothing co-resident to hide under, and the whole block
// parks at each barrier. This re-tile keeps the verified round-9 inner math byte-identical
// and only changes geometry: 256-thread blocks (4 waves x 32 q-rows), grid 512 = 2 blocks/CU
// (16 waves/CU): independent per-block barriers de-stagger, 2x latency-hiding.
__global__ __launch_bounds__(256, 4) void flash_attn(
    const unsigned short* __restrict__ Qb, const unsigned short* __restrict__ Kb,
    const unsigned short* __restrict__ Vt, const unsigned* __restrict__ Mb,
    unsigned short* __restrict__ Ab){
    __shared__ unsigned short Kt[2][64*64];
    __shared__ unsigned short Vl[2][64*64];
    __shared__ uint2 mlut[16];

    const int tid = threadIdx.x;
    if (tid < 16){
        uint2 e;
        e.x = ((tid & 1) ? 0xFFFFu : 0u) | ((tid & 2) ? 0xFFFF0000u : 0u);
        e.y = ((tid & 4) ? 0xFFFFu : 0u) | ((tid & 8) ? 0xFFFF0000u : 0u);
        mlut[tid] = e;
    }

    // XCD-aware remap: flat [0,512); each XCD owns 4 (n,h) slices x 16 qt-blocks.
    const int flat = blockIdx.x + (blockIdx.y << 4);  // grid (16, 32)
    const int xcd = flat & 7, idx = flat >> 3;        // idx [0,64)
    const int qt = idx & 15;
    const int sl = xcd + ((idx >> 4) << 3);           // [0,32)
    const int h = sl & 15, n = sl >> 4;

    const int wave = tid >> 6, lane = tid & 63;
    const int l31 = lane & 31, hi = lane >> 5;
    const int qbase = qt*128 + wave*32;
    const int q = qbase + l31;

    const unsigned short* Qh = Qb + (n*NHEAD + h)*S_LEN*DHEAD;
    const unsigned short* Kh = Kb + (n*NHEAD + h)*S_LEN*DHEAD;
    const unsigned short* Vh = Vt + (n*NHEAD + h)*DHEAD*S_LEN;
    const unsigned* mr = Mb + (size_t)(n*S_LEN + q)*(S_LEN/32);

    // staging: 256 threads x 2 uint4 each for K and V (row srow, chunks sch and sch+4)
    const int srow = tid >> 2, sch = tid & 3;
    const int sd0 = srow*64 + ((sch       ^ (srow & 7))*8);
    const int sd1 = srow*64 + (((sch + 4) ^ (srow & 7))*8);

    bf16x8 Qf[4];
#pragma unroll
    for (int g = 0; g < 4; g++)
        Qf[g] = *(const bf16x8*)(Qh + q*DHEAD + g*16 + hi*8);

    f32x16 accO0 = (f32x16)0.0f, accO1 = (f32x16)0.0f, accL = (f32x16)0.0f;
    const short onev = 0x3F80;
    const bf16x8 ones8 = {onev,onev,onev,onev,onev,onev,onev,onev};

    uint4 kpre0 = *(const uint4*)(Kh + srow*DHEAD + sch*8);
    uint4 kpre1 = *(const uint4*)(Kh + srow*DHEAD + sch*8 + 32);
    uint4 vpre0 = *(const uint4*)(Vh + srow*S_LEN + sch*8);
    uint4 vpre1 = *(const uint4*)(Vh + srow*S_LEN + sch*8 + 32);

    int c = 0;
    for (int kb = 0; kb < S_LEN; kb += 64){
        *(uint4*)&Kt[c][sd0] = kpre0;
        *(uint4*)&Kt[c][sd1] = kpre1;
        *(uint4*)&Vl[c][sd0] = vpre0;
        *(uint4*)&Vl[c][sd1] = vpre1;
        __syncthreads();   // nothing in flight: barrier drain free (round-8 fix)
        if (kb + 64 < S_LEN){
            kpre0 = *(const uint4*)(Kh + (kb + 64 + srow)*DHEAD + sch*8);
            kpre1 = *(const uint4*)(Kh + (kb + 64 + srow)*DHEAD + sch*8 + 32);
            vpre0 = *(const uint4*)(Vh + srow*S_LEN + kb + 64 + sch*8);
            vpre1 = *(const uint4*)(Vh + srow*S_LEN + kb + 64 + sch*8 + 32);
        }
        uint2 mw = *(const uint2*)(mr + (kb >> 5));

        f32x16 e0 = (f32x16)0.0f, e1 = (f32x16)0.0f;
#pragma unroll
        for (int g = 0; g < 4; g++){
            const int ch = g*2 + hi;
            const int r0 = l31, r1 = 32 + l31;
            bf16x8 kf0 = *(const bf16x8*)&Kt[c][r0*64 + ((ch ^ (r0 & 7))*8)];
            bf16x8 kf1 = *(const bf16x8*)&Kt[c][r1*64 + ((ch ^ (r1 & 7))*8)];
            e0 = MFMA32(kf0, Qf[g], e0);
            e1 = MFMA32(kf1, Qf[g], e1);
        }

        unsigned pw[2][4][2];
#pragma unroll
        for (int t = 0; t < 2; t++){
            const f32x16 ev = t ? e1 : e0;
            unsigned sh = (t ? mw.y : mw.x) >> (4*hi);
#pragma unroll
            for (int s = 0; s < 4; s++){
                uint2 m = mlut[(sh >> (8*s)) & 0xFu];
                float p0 = fast_exp2(ev[4*s+0]);
                float p1 = fast_exp2(ev[4*s+1]);
                float p2 = fast_exp2(ev[4*s+2]);
                float p3 = fast_exp2(ev[4*s+3]);
                pw[t][s][0] = pk2bf(p0, p1) & m.x;
                pw[t][s][1] = pk2bf(p2, p3) & m.y;
            }
        }

#pragma unroll
        for (int t = 0; t < 2; t++){
#pragma unroll
            for (int gg = 0; gg < 2; gg++){
                unsigned a0 = pw[t][2*gg][0],   b0 = pw[t][2*gg+1][0];
                unsigned a1 = pw[t][2*gg][1],   b1 = pw[t][2*gg+1][1];
                asm volatile("v_permlane32_swap_b32 %0, %1" : "+v"(a0), "+v"(b0));
                asm volatile("v_permlane32_swap_b32 %0, %1" : "+v"(a1), "+v"(b1));
                uint4 af; af.x = a0; af.y = a1; af.z = b0; af.w = b1;
                bf16x8 Pa = *(bf16x8*)&af;
                const int kg = t*2 + gg;
                const int ch = kg*2 + hi;
                const int d0 = l31, d1 = 32 + l31;
                bf16x8 vf0 = *(const bf16x8*)&Vl[c][d0*64 + ((ch ^ (d0 & 7))*8)];
                bf16x8 vf1 = *(const bf16x8*)&Vl[c][d1*64 + ((ch ^ (d1 & 7))*8)];
                accO0 = MFMA32(Pa, vf0, accO0);
                accO1 = MFMA32(Pa, vf1, accO1);
                accL  = MFMA32(Pa, ones8, accL);
            }
        }
        c ^= 1;
    }

#pragma unroll
    for (int r = 0; r < 16; r++){
        float inv = fast_rcp(accL[r]);
        int qrow = qbase + (r & 3) + 8*(r >> 2) + 4*hi;
        unsigned short* dst = Ab + (size_t)(n*S_LEN + qrow)*EMB + h*DHEAD + l31;
        dst[0]  = f2bf(accO0[r]*inv);
        dst[32] = f2bf(accO1[r]*inv);
    }
}

// ---------------- output GEMM: flash-style LDS-staged 128x128 tile (unchanged, passing) ---
__global__ __launch_bounds__(512, 1) void gemm_out(
    const unsigned short* __restrict__ Ab, const unsigned short* __restrict__ W,
    const float* __restrict__ bias, float* __restrict__ out){
    __shared__ unsigned short At[2][128*64];
    __shared__ unsigned short Wt[2][128*64];

    const int flat = blockIdx.x + (blockIdx.y << 3);  // grid (8, 32) -> [0,256)
    const int xcd = flat & 7, idx = flat >> 3;        // idx [0,32)
    const int nb = idx & 7, mbt = xcd*4 + (idx >> 3); // bijective: 8 XCD x 4 mb x 8 nb
    const int tid = threadIdx.x;
    const int wave = tid >> 6, lane = tid & 63;
    const int l31 = lane & 31, hi = lane >> 5;
    const int wm = wave & 3, wn = wave >> 2;
    const int mbase = mbt*128, nbase = nb*128;
    const int am = wm*32, n0 = wn*64;

    const int srow = tid >> 2, sch = tid & 3;
    const int d0 = srow*64 + ((sch       ^ (srow & 7))*8);
    const int d1 = srow*64 + (((sch + 4) ^ (srow & 7))*8);
    const unsigned short* Asrc = Ab + (size_t)(mbase + srow)*EMB + sch*8;
    const unsigned short* Wsrc = W  + (size_t)(nbase + srow)*EMB + sch*8;

    f32x16 acc0 = (f32x16)0.0f, acc1 = (f32x16)0.0f;

    uint4 apre0 = *(const uint4*)(Asrc);
    uint4 apre1 = *(const uint4*)(Asrc + 32);
    uint4 wpre0 = *(const uint4*)(Wsrc);
    uint4 wpre1 = *(const uint4*)(Wsrc + 32);

    int c = 0;
    for (int kb = 0; kb < EMB; kb += 64){
        *(uint4*)&At[c][d0] = apre0;
        *(uint4*)&At[c][d1] = apre1;
        *(uint4*)&Wt[c][d0] = wpre0;
        *(uint4*)&Wt[c][d1] = wpre1;
        __syncthreads();   // nothing in flight: barrier drain free
        if (kb + 64 < EMB){
            apre0 = *(const uint4*)(Asrc + kb + 64);
            apre1 = *(const uint4*)(Asrc + kb + 64 + 32);
            wpre0 = *(const uint4*)(Wsrc + kb + 64);
            wpre1 = *(const uint4*)(Wsrc + kb + 64 + 32);
        }
#pragma unroll
        for (int kg = 0; kg < 4; kg++){
            const int ch = kg*2 + hi;
            const int ra = am + l31, r0 = n0 + l31, r1 = n0 + 32 + l31;
            bf16x8 Af  = *(const bf16x8*)&At[c][ra*64 + ((ch ^ (ra & 7))*8)];
            bf16x8 Wf0 = *(const bf16x8*)&Wt[c][r0*64 + ((ch ^ (r0 & 7))*8)];
            bf16x8 Wf1 = *(const bf16x8*)&Wt[c][r1*64 + ((ch ^ (r1 & 7))*8)];
            acc0 = MFMA32(Af, Wf0, acc0);
            acc1 = MFMA32(Af, Wf1, acc1);
        }
        c ^= 1;
    }

    const float b0 = bias[nbase + n0 + l31];
    const float b1 = bias[nbase + n0 + 32 + l31];
#pragma unroll
    for (int r = 0; r < 16; r++){
        int mrow = mbase + am + (r & 3) + 8*(r >> 2) + 4*hi;
        float* dst = &out[(size_t)mrow*EMB + nbase + n0 + l31];
        dst[0]  = acc0[r] + b0;
        dst[32] = acc1[r] + b1;
    }
}

extern "C" void kernel_launch(void* const* d_in, const int* in_sizes, int n_in,
                              void* d_out, int out_size, void* d_ws, size_t ws_size,
                              hipStream_t stream){
    const float* values = (const float*)d_in[0];
    const float* keys   = (const float*)d_in[1];
    const float* query  = (const float*)d_in[2];
    const int*   mask   = (const int*)d_in[3];
    const float* W_fc   = (const float*)d_in[4];
    const float* b_fc   = (const float*)d_in[5];
    float* out = (float*)d_out;

    char* ws = (char*)d_ws;
    unsigned short* Qb  = (unsigned short*)(ws);                        // 8 MiB
    unsigned short* Kb  = (unsigned short*)(ws + (8ull  << 20));        // 8 MiB
    unsigned short* Vtb = (unsigned short*)(ws + (16ull << 20));        // 8 MiB
    unsigned short* Wb  = (unsigned short*)(ws + (24ull << 20));        // 2 MiB
    unsigned*       Mb  = (unsigned*)      (ws + (26ull << 20));        // 1 MiB (bit-packed mask)
    unsigned short* Ab  = (unsigned short*)(ws + (27ull << 20));        // 8 MiB normalized bf16 O

    prep_all  <<<7168, 256, 0, stream>>>(query, keys, values, mask, W_fc,
                                         Qb, Kb, Vtb, Wb, Mb);
    flash_attn<<<dim3(16, 32), 256, 0, stream>>>(Qb, Kb, Vtb, Mb, Ab);
    gemm_out  <<<dim3(8, 32), 512, 0, stream>>>(Ab, Wb, b_fc, out);
}

// Round 13
// 193.959 us; speedup vs baseline: 1.2740x; 1.2740x over previous
//
#include <hip/hip_runtime.h>
#include <cmath>

#define S_LEN 2048
#define EMB   1024
#define NHEAD 16
#define DHEAD 64

typedef __attribute__((ext_vector_type(8)))  short bf16x8;
typedef __attribute__((ext_vector_type(4)))  short bf16x4;
typedef __attribute__((ext_vector_type(4)))  float f32x4;
typedef __attribute__((ext_vector_type(16))) float f32x16;

#define MFMA32(a,b,c) __builtin_amdgcn_mfma_f32_32x32x16_bf16(a,b,c,0,0,0)

__device__ __forceinline__ unsigned short f2bf(float f){
    union { float f; unsigned u; } v; v.f = f;
    unsigned r = v.u + 0x7fffu + ((v.u >> 16) & 1u);
    return (unsigned short)(r >> 16);
}

__device__ __forceinline__ unsigned pk2bf(float a, float b){
#if __has_builtin(__builtin_amdgcn_cvt_pk_bf16_f32)
    typedef __attribute__((ext_vector_type(2))) __bf16 bf2;
    bf2 r = __builtin_amdgcn_cvt_pk_bf16_f32(a, b);
    return *(unsigned*)&r;
#else
    return (unsigned)f2bf(a) | ((unsigned)f2bf(b) << 16);
#endif
}

__device__ __forceinline__ float fast_exp2(float x){
#if __has_builtin(__builtin_amdgcn_exp2f)
    return __builtin_amdgcn_exp2f(x);
#else
    return exp2f(x);
#endif
}

__device__ __forceinline__ float fast_rcp(float x){
#if __has_builtin(__builtin_amdgcn_rcpf)
    return __builtin_amdgcn_rcpf(x);
#else
    return 1.0f / x;
#endif
}

// ---------------- fused prep: range-dispatched over blockIdx.x (unchanged, passing) -------
__global__ void prep_all(const float* __restrict__ q, const float* __restrict__ k,
                         const float* __restrict__ v, const int* __restrict__ mask,
                         const float* __restrict__ W,
                         unsigned short* __restrict__ Qb, unsigned short* __restrict__ Kb,
                         unsigned short* __restrict__ Vt, unsigned short* __restrict__ Wb,
                         unsigned* __restrict__ Mb){
    __shared__ unsigned short tile[64*68];
    const int b = blockIdx.x, tid = threadIdx.x;
    if (b < 4096){
        const float SC = 0.045084220027780106f;   // log2(e)/32
        int base = (b*256 + tid) * 4;
        int e = base & (EMB - 1);
        int s = (base >> 10) & (S_LEN - 1);
        int n = base >> 21;
        int h = e >> 6, d = e & 63;
        int dst = ((n*NHEAD + h)*S_LEN + s)*DHEAD + d;
        float4 qv = *(const float4*)(q + base);
        float4 kv = *(const float4*)(k + base);
        uint2 qp, kp;
        qp.x = pk2bf(qv.x*SC, qv.y*SC);
        qp.y = pk2bf(qv.z*SC, qv.w*SC);
        kp.x = pk2bf(kv.x, kv.y);
        kp.y = pk2bf(kv.z, kv.w);
        *(uint2*)(Qb + dst) = qp;
        *(uint2*)(Kb + dst) = kp;
    } else if (b < 5120){
        int idx = b - 4096;
        int st = idx & 31, h = (idx >> 5) & 15, n = idx >> 9;
        int sbase = st * 64;
#pragma unroll
        for (int i = 0; i < 4; i++){
            int c = tid + i*256;
            int srow = c >> 4, c4 = (c & 15) * 4;
            float4 x = *(const float4*)(v + (n*S_LEN + sbase + srow)*EMB + h*DHEAD + c4);
            uint2 p;
            p.x = pk2bf(x.x, x.y);
            p.y = pk2bf(x.z, x.w);
            *(uint2*)&tile[srow*68 + c4] = p;
        }
        __syncthreads();
#pragma unroll
        for (int i = 0; i < 2; i++){
            int c = tid + i*256;
            int d = c >> 3, s8 = (c & 7) * 8;
            unsigned u0 = (unsigned)tile[(s8+0)*68 + d] | ((unsigned)tile[(s8+1)*68 + d] << 16);
            unsigned u1 = (unsigned)tile[(s8+2)*68 + d] | ((unsigned)tile[(s8+3)*68 + d] << 16);
            unsigned u2 = (unsigned)tile[(s8+4)*68 + d] | ((unsigned)tile[(s8+5)*68 + d] << 16);
            unsigned u3 = (unsigned)tile[(s8+6)*68 + d] | ((unsigned)tile[(s8+7)*68 + d] << 16);
            uint4 pk; pk.x = u0; pk.y = u1; pk.z = u2; pk.w = u3;
            *(uint4*)(Vt + ((n*NHEAD + h)*DHEAD + d)*S_LEN + sbase + s8) = pk;
        }
    } else if (b < 6144){
        int base = ((b - 5120)*256 + tid) * 4;
        float4 x = *(const float4*)(W + base);
        uint2 p;
        p.x = pk2bf(x.x, x.y);
        p.y = pk2bf(x.z, x.w);
        *(uint2*)(Wb + base) = p;
    } else {
        int u = (b - 6144)*256 + tid;                 // [0, 262144)
        const int4* m4 = (const int4*)mask + (size_t)u*8;
        unsigned w = 0;
#pragma unroll
        for (int i = 0; i < 8; i++){
            int4 m = m4[i];
            unsigned nib = (m.x ? 1u : 0u) | (m.y ? 2u : 0u) | (m.z ? 4u : 0u) | (m.w ? 8u : 0u);
            w |= nib << (i*4);
        }
        Mb[u] = w;
    }
}

// ---------------- flash attention: round-11 core, BK=128 phase-merge ----------------------
// ROUND-13: revert round-12's re-tile (it doubled staging AND added zero waves/CU — 512x4
// == 256x8 waves). Geometry is round-11's verified 61 us config: grid 256 (1/CU), 512
// threads = 8 waves x 32 q-rows. ONE lever added: stage TWO 64-k subtiles per barrier
// (BK=128). Same staging bytes, half the barriers (16 vs 32), and PV(sub0) / QK(sub1)
// become independent streams inside a phase -> scheduler fills PV's dependent tail with
// QK MFMAs and overlaps sub1 softmax VALU under sub0 PV. Inner body byte-identical to
// round-11; mask uint2 becomes the two halves of one aligned uint4.
__global__ __launch_bounds__(512, 2) void flash_attn(
    const unsigned short* __restrict__ Qb, const unsigned short* __restrict__ Kb,
    const unsigned short* __restrict__ Vt, const unsigned* __restrict__ Mb,
    unsigned short* __restrict__ Ab){
    __shared__ unsigned short Kt[2][2][64*64];
    __shared__ unsigned short Vl[2][2][64*64];
    __shared__ uint2 mlut[16];

    const int tid = threadIdx.x;
    if (tid < 16){
        uint2 e;
        e.x = ((tid & 1) ? 0xFFFFu : 0u) | ((tid & 2) ? 0xFFFF0000u : 0u);
        e.y = ((tid & 4) ? 0xFFFFu : 0u) | ((tid & 8) ? 0xFFFF0000u : 0u);
        mlut[tid] = e;
    }

    const int flat = blockIdx.x + (blockIdx.y << 3);  // grid (8, 32)
    const int xcd = flat & 7, idx = flat >> 3;
    const int qt = idx & 7;
    const int sl = xcd + ((idx >> 3) << 3);
    const int h = sl & 15, n = sl >> 4;

    const int wave = tid >> 6, lane = tid & 63;
    const int l31 = lane & 31, hi = lane >> 5;
    const int qbase = qt*256 + wave*32;
    const int q = qbase + l31;

    const unsigned short* Qh = Qb + (n*NHEAD + h)*S_LEN*DHEAD;
    const unsigned short* Kh = Kb + (n*NHEAD + h)*S_LEN*DHEAD;
    const unsigned short* Vh = Vt + (n*NHEAD + h)*DHEAD*S_LEN;
    const unsigned* mr = Mb + (size_t)(n*S_LEN + q)*(S_LEN/32);

    const int srow = tid >> 3, schunk = tid & 7;
    const int sdst = srow*64 + ((schunk ^ (srow & 7)) * 8);

    bf16x8 Qf[4];
#pragma unroll
    for (int g = 0; g < 4; g++)
        Qf[g] = *(const bf16x8*)(Qh + q*DHEAD + g*16 + hi*8);

    f32x16 accO0 = (f32x16)0.0f, accO1 = (f32x16)0.0f, accL = (f32x16)0.0f;
    const short onev = 0x3F80;
    const bf16x8 ones8 = {onev,onev,onev,onev,onev,onev,onev,onev};

    uint4 kpre0 = *(const uint4*)(Kh + srow*DHEAD + schunk*8);
    uint4 kpre1 = *(const uint4*)(Kh + (64 + srow)*DHEAD + schunk*8);
    uint4 vpre0 = *(const uint4*)(Vh + srow*S_LEN + schunk*8);
    uint4 vpre1 = *(const uint4*)(Vh + srow*S_LEN + 64 + schunk*8);

    int c = 0;
    for (int kb = 0; kb < S_LEN; kb += 128){
        *(uint4*)&Kt[c][0][sdst] = kpre0;
        *(uint4*)&Kt[c][1][sdst] = kpre1;
        *(uint4*)&Vl[c][0][sdst] = vpre0;
        *(uint4*)&Vl[c][1][sdst] = vpre1;
        __syncthreads();   // nothing in flight: barrier drain free (round-8 fix)
        if (kb + 128 < S_LEN){
            kpre0 = *(const uint4*)(Kh + (kb + 128 + srow)*DHEAD + schunk*8);
            kpre1 = *(const uint4*)(Kh + (kb + 192 + srow)*DHEAD + schunk*8);
            vpre0 = *(const uint4*)(Vh + srow*S_LEN + kb + 128 + schunk*8);
            vpre1 = *(const uint4*)(Vh + srow*S_LEN + kb + 192 + schunk*8);
        }
        uint4 mq = *(const uint4*)(mr + (kb >> 5));   // 128 mask bits for this lane's q-row

#pragma unroll
        for (int sub = 0; sub < 2; sub++){
            const unsigned short* Ktc = Kt[c][sub];
            const unsigned short* Vlc = Vl[c][sub];
            const unsigned mwx = sub ? mq.z : mq.x;
            const unsigned mwy = sub ? mq.w : mq.y;

            f32x16 e0 = (f32x16)0.0f, e1 = (f32x16)0.0f;
#pragma unroll
            for (int g = 0; g < 4; g++){
                const int ch = g*2 + hi;
                const int r0 = l31, r1 = 32 + l31;
                bf16x8 kf0 = *(const bf16x8*)&Ktc[r0*64 + ((ch ^ (r0 & 7))*8)];
                bf16x8 kf1 = *(const bf16x8*)&Ktc[r1*64 + ((ch ^ (r1 & 7))*8)];
                e0 = MFMA32(kf0, Qf[g], e0);
                e1 = MFMA32(kf1, Qf[g], e1);
            }

            unsigned pw[2][4][2];
#pragma unroll
            for (int t = 0; t < 2; t++){
                const f32x16 ev = t ? e1 : e0;
                unsigned sh = (t ? mwy : mwx) >> (4*hi);
#pragma unroll
                for (int s = 0; s < 4; s++){
                    uint2 m = mlut[(sh >> (8*s)) & 0xFu];
                    float p0 = fast_exp2(ev[4*s+0]);
                    float p1 = fast_exp2(ev[4*s+1]);
                    float p2 = fast_exp2(ev[4*s+2]);
                    float p3 = fast_exp2(ev[4*s+3]);
                    pw[t][s][0] = pk2bf(p0, p1) & m.x;
                    pw[t][s][1] = pk2bf(p2, p3) & m.y;
                }
            }

#pragma unroll
            for (int t = 0; t < 2; t++){
#pragma unroll
                for (int gg = 0; gg < 2; gg++){
                    unsigned a0 = pw[t][2*gg][0],   b0 = pw[t][2*gg+1][0];
                    unsigned a1 = pw[t][2*gg][1],   b1 = pw[t][2*gg+1][1];
                    asm volatile("v_permlane32_swap_b32 %0, %1" : "+v"(a0), "+v"(b0));
                    asm volatile("v_permlane32_swap_b32 %0, %1" : "+v"(a1), "+v"(b1));
                    uint4 af; af.x = a0; af.y = a1; af.z = b0; af.w = b1;
                    bf16x8 Pa = *(bf16x8*)&af;
                    const int kg = t*2 + gg;
                    const int ch = kg*2 + hi;
                    const int d0 = l31, d1 = 32 + l31;
                    bf16x8 vf0 = *(const bf16x8*)&Vlc[d0*64 + ((ch ^ (d0 & 7))*8)];
                    bf16x8 vf1 = *(const bf16x8*)&Vlc[d1*64 + ((ch ^ (d1 & 7))*8)];
                    accO0 = MFMA32(Pa, vf0, accO0);
                    accO1 = MFMA32(Pa, vf1, accO1);
                    accL  = MFMA32(Pa, ones8, accL);
                }
            }
        }
        c ^= 1;
    }

#pragma unroll
    for (int r = 0; r < 16; r++){
        float inv = fast_rcp(accL[r]);
        int qrow = qbase + (r & 3) + 8*(r >> 2) + 4*hi;
        unsigned short* dst = Ab + (size_t)(n*S_LEN + qrow)*EMB + h*DHEAD + l31;
        dst[0]  = f2bf(accO0[r]*inv);
        dst[32] = f2bf(accO1[r]*inv);
    }
}

// ---------------- output GEMM: flash-style LDS-staged 128x128 tile (unchanged, passing) ---
__global__ __launch_bounds__(512, 1) void gemm_out(
    const unsigned short* __restrict__ Ab, const unsigned short* __restrict__ W,
    const float* __restrict__ bias, float* __restrict__ out){
    __shared__ unsigned short At[2][128*64];
    __shared__ unsigned short Wt[2][128*64];

    const int flat = blockIdx.x + (blockIdx.y << 3);  // grid (8, 32) -> [0,256)
    const int xcd = flat & 7, idx = flat >> 3;        // idx [0,32)
    const int nb = idx & 7, mbt = xcd*4 + (idx >> 3); // bijective: 8 XCD x 4 mb x 8 nb
    const int tid = threadIdx.x;
    const int wave = tid >> 6, lane = tid & 63;
    const int l31 = lane & 31, hi = lane >> 5;
    const int wm = wave & 3, wn = wave >> 2;
    const int mbase = mbt*128, nbase = nb*128;
    const int am = wm*32, n0 = wn*64;

    const int srow = tid >> 2, sch = tid & 3;
    const int d0 = srow*64 + ((sch       ^ (srow & 7))*8);
    const int d1 = srow*64 + (((sch + 4) ^ (srow & 7))*8);
    const unsigned short* Asrc = Ab + (size_t)(mbase + srow)*EMB + sch*8;
    const unsigned short* Wsrc = W  + (size_t)(nbase + srow)*EMB + sch*8;

    f32x16 acc0 = (f32x16)0.0f, acc1 = (f32x16)0.0f;

    uint4 apre0 = *(const uint4*)(Asrc);
    uint4 apre1 = *(const uint4*)(Asrc + 32);
    uint4 wpre0 = *(const uint4*)(Wsrc);
    uint4 wpre1 = *(const uint4*)(Wsrc + 32);

    int c = 0;
    for (int kb = 0; kb < EMB; kb += 64){
        *(uint4*)&At[c][d0] = apre0;
        *(uint4*)&At[c][d1] = apre1;
        *(uint4*)&Wt[c][d0] = wpre0;
        *(uint4*)&Wt[c][d1] = wpre1;
        __syncthreads();   // nothing in flight: barrier drain free
        if (kb + 64 < EMB){
            apre0 = *(const uint4*)(Asrc + kb + 64);
            apre1 = *(const uint4*)(Asrc + kb + 64 + 32);
            wpre0 = *(const uint4*)(Wsrc + kb + 64);
            wpre1 = *(const uint4*)(Wsrc + kb + 64 + 32);
        }
#pragma unroll
        for (int kg = 0; kg < 4; kg++){
            const int ch = kg*2 + hi;
            const int ra = am + l31, r0 = n0 + l31, r1 = n0 + 32 + l31;
            bf16x8 Af  = *(const bf16x8*)&At[c][ra*64 + ((ch ^ (ra & 7))*8)];
            bf16x8 Wf0 = *(const bf16x8*)&Wt[c][r0*64 + ((ch ^ (r0 & 7))*8)];
            bf16x8 Wf1 = *(const bf16x8*)&Wt[c][r1*64 + ((ch ^ (r1 & 7))*8)];
            acc0 = MFMA32(Af, Wf0, acc0);
            acc1 = MFMA32(Af, Wf1, acc1);
        }
        c ^= 1;
    }

    const float b0 = bias[nbase + n0 + l31];
    const float b1 = bias[nbase + n0 + 32 + l31];
#pragma unroll
    for (int r = 0; r < 16; r++){
        int mrow = mbase + am + (r & 3) + 8*(r >> 2) + 4*hi;
        float* dst = &out[(size_t)mrow*EMB + nbase + n0 + l31];
        dst[0]  = acc0[r] + b0;
        dst[32] = acc1[r] + b1;
    }
}

extern "C" void kernel_launch(void* const* d_in, const int* in_sizes, int n_in,
                              void* d_out, int out_size, void* d_ws, size_t ws_size,
                              hipStream_t stream){
    const float* values = (const float*)d_in[0];
    const float* keys   = (const float*)d_in[1];
    const float* query  = (const float*)d_in[2];
    const int*   mask   = (const int*)d_in[3];
    const float* W_fc   = (const float*)d_in[4];
    const float* b_fc   = (const float*)d_in[5];
    float* out = (float*)d_out;

    char* ws = (char*)d_ws;
    unsigned short* Qb  = (unsigned short*)(ws);                        // 8 MiB
    unsigned short* Kb  = (unsigned short*)(ws + (8ull  << 20));        // 8 MiB
    unsigned short* Vtb = (unsigned short*)(ws + (16ull << 20));        // 8 MiB
    unsigned short* Wb  = (unsigned short*)(ws + (24ull << 20));        // 2 MiB
    unsigned*       Mb  = (unsigned*)      (ws + (26ull << 20));        // 1 MiB (bit-packed mask)
    unsigned short* Ab  = (unsigned short*)(ws + (27ull << 20));        // 8 MiB normalized bf16 O

    prep_all  <<<7168, 256, 0, stream>>>(query, keys, values, mask, W_fc,
                                         Qb, Kb, Vtb, Wb, Mb);
    flash_attn<<<dim3(8, 32), 512, 0, stream>>>(Qb, Kb, Vtb, Mb, Ab);
    gemm_out  <<<dim3(8, 32), 512, 0, stream>>>(Ab, Wb, b_fc, out);
}